// Round 8
// baseline (265.163 us; speedup 1.0000x reference)
//
#include <hip/hip_runtime.h>
#include <hip/hip_fp16.h>

#define NDIM 8192
#define KDIM 8192
#define NT 256          // N / 32 hash tiles
#define MOD2 4193281    // HASH_SIZE - 32*32 + 1
#define PRIME 2038074743LL

#define BM 256
#define BN 128
#define BK 32
#define KITER 64        // (KDIM/4)/BK, split-K = 4
#define BSLAB 1032      // halves per k-octet slab (128*8 + 8 pad; phase-balanced)

typedef _Float16 half8 __attribute__((ext_vector_type(8)));
typedef float floatx4 __attribute__((ext_vector_type(4)));

// ---------------- fused prepass: cvt fp32->f16, out=bias, ROBE-Z starts ----------------
__global__ __launch_bounds__(256) void prep_kernel(const float* __restrict__ x,
                                                   const float* __restrict__ hw,
                                                   const float* __restrict__ bias,
                                                   const int* __restrict__ rn,
                                                   __half* __restrict__ xh,
                                                   __half* __restrict__ hh,
                                                   int* __restrict__ starts,
                                                   float* __restrict__ out) {
    int b = blockIdx.x;
    int tid = threadIdx.x;
    if (b < 8192) {                       // cvt: 2M threads x 4 floats
        int i = b * 256 + tid;
        const float4* s; __half2* d; int j;
        if (i < (1 << 20)) { s = (const float4*)x;  d = (__half2*)xh; j = i; }
        else               { s = (const float4*)hw; d = (__half2*)hh; j = i - (1 << 20); }
        float4 v = s[j];
        d[j * 2]     = __floats2half2_rn(v.x, v.y);
        d[j * 2 + 1] = __floats2half2_rn(v.z, v.w);
    } else if (b < 8192 + 4096) {         // init: out = bias (atomic targets)
        int i = (b - 8192) * 256 + tid;
        float4 bv = *(const float4*)(bias + ((i & 2047) << 2));
        ((float4*)out)[i] = bv;
    } else {                              // starts: 64K hash tile offsets
        int t = (b - 12288) * 256 + tid;
        bool is64 = (rn[1] == 0 && rn[3] == 0);   // int64 input: words 1,3 are hi-halves
        long long R1 = is64 ? rn[2] : rn[1];
        long long R2 = is64 ? rn[4] : rn[2];
        long long R3 = is64 ? rn[6] : rn[3];
        long long k_id = t >> 8, n_id = t & 255;
        long long v = (k_id * R3 + n_id * R2 + R1) % PRIME;
        starts[t] = (int)(v % MOD2);
    }
}

// ---------------- main GEMM: split-K=4, 256x128 block ----------------
// A operand: NO LDS — dist-1 register prefetch of MFMA fragments straight from
// global (row-major xh; wn-wave-pairs read identical lines -> L1; xh L2-resident).
// B operand: R7-verbatim (gather + transpose-pack + swizzled LDS, dist-2 prefetch).
// This halves LDS-read bytes (the saturated pipe at R7's 122us).
__global__ __launch_bounds__(512, 4) void gemm_kernel(
    const __half* __restrict__ xh, const __half* __restrict__ hh,
    const int* __restrict__ starts, float* __restrict__ out) {
    __shared__ __align__(16) __half Bs[2][4 * BSLAB];      // [k-octet][n][8] k-runs, swizzled
    __shared__ int Ss[KITER * 4];                          // per-block starts table

    const int tid = threadIdx.x;
    const int lane = tid & 63;
    const int wave = tid >> 6;       // 0..7
    const int wm = wave >> 1;        // 0..3 : 64-row strip
    const int wn = wave & 1;         // 0..1 : 64-col strip
    const int quad = lane >> 4;
    const int l16 = lane & 15;

    const int i = blockIdx.x;        // 512 blocks
    const int ks = i & 3;
    const int m_blk = (i >> 2) & 1;
    const int n_blk = i >> 3;        // 0..63
    const int gm0 = m_blk * BM;
    const int gn0 = n_blk * BN;
    const int kt0 = ks * KITER;
    const int n_id0 = n_blk * 4;     // 4 hash tiles per block

    if (tid < KITER * 4) {
        int kp = tid >> 2, tile = tid & 3;
        Ss[tid] = starts[(kt0 + kp) * NT + n_id0 + tile];
    }

    // ---- A fragments: direct global, MFMA layout (row=wm*64+r*16+l16, k=quad*8) ----
    const __half* a_base = xh + (size_t)(gm0 + wm * 64 + l16) * KDIM + kt0 * 32 + quad * 8;

#define LOADA(F0, F1, F2, F3, kp_) do {                                        \
        const __half* ap = a_base + (kp_) * 32;                                \
        F0 = *(const half8*)(ap);                                              \
        F1 = *(const half8*)(ap + (size_t)16 * KDIM);                          \
        F2 = *(const half8*)(ap + (size_t)32 * KDIM);                          \
        F3 = *(const half8*)(ap + (size_t)48 * KDIM);                          \
    } while (0)

    // ---- B staging (reg-staged pack, R7-verbatim) ----
    const int b_tile = tid >> 7;              // 0..3
    const int t7 = tid & 127;
    const int b_np = t7 & 15;                 // n-pair
    const int b_kg = t7 >> 4;                 // 0..7 : 4-k group
    const int b_oct = b_kg >> 1;
    const unsigned b_base = b_oct * BSLAB;
    const unsigned b_pos = (b_tile * 32 + 2 * b_np) * 8 + (b_kg & 1) * 4;
    const unsigned bswz = (b_np & 4) << 1;    // = (n_even & 8)

    unsigned pbA0, pbA1, pbA2, pbA3, pbB0, pbB1, pbB2, pbB3;
    half8 afA0, afA1, afA2, afA3, afB0, afB1, afB2, afB3;

#define LOADT(Q0, Q1, Q2, Q3, kp_) do {                                        \
        int st = Ss[(kp_) * 4 + b_tile];                                       \
        const __half* src = hh + st + b_kg * 128 + b_np * 2;                   \
        Q0 = *(const unsigned*)(src);                                          \
        Q1 = *(const unsigned*)(src + 32);                                     \
        Q2 = *(const unsigned*)(src + 64);                                     \
        Q3 = *(const unsigned*)(src + 96);                                     \
    } while (0)

#define STORET(Q0, Q1, Q2, Q3, buf_) do {                                      \
        unsigned lo0 = (Q0 & 0xffffu) | (Q1 << 16);                            \
        unsigned lo1 = (Q2 & 0xffffu) | (Q3 << 16);                            \
        unsigned hi0 = (Q0 >> 16) | (Q1 & 0xffff0000u);                        \
        unsigned hi1 = (Q2 >> 16) | (Q3 & 0xffff0000u);                        \
        uint2 e = {lo0, lo1}, o = {hi0, hi1};                                  \
        *(uint2*)&Bs[buf_][b_base + (b_pos ^ bswz)] = e;                       \
        *(uint2*)&Bs[buf_][b_base + ((b_pos + 8) ^ bswz)] = o;                 \
    } while (0)

    floatx4 acc[4][4];
#pragma unroll
    for (int r = 0; r < 4; r++)
#pragma unroll
        for (int c = 0; c < 4; c++)
            acc[r][c] = (floatx4){0.f, 0.f, 0.f, 0.f};

    const unsigned rswz = (unsigned)(l16 & 8);        // B read swizzle (R6)

#define FRAGS_MFMA(buf_, F0, F1, F2, F3) do {                                  \
        half8 bf[4];                                                           \
        _Pragma("unroll")                                                      \
        for (int c = 0; c < 4; c++)                                            \
            bf[c] = *(const half8*)&Bs[buf_][quad * BSLAB + ((unsigned)((wn * 64 + c * 16 + l16) * 8) ^ rswz)]; \
        _Pragma("unroll")                                                      \
        for (int c = 0; c < 4; c++) {                                          \
            acc[0][c] = __builtin_amdgcn_mfma_f32_16x16x32_f16(F0, bf[c], acc[0][c], 0, 0, 0); \
            acc[1][c] = __builtin_amdgcn_mfma_f32_16x16x32_f16(F1, bf[c], acc[1][c], 0, 0, 0); \
            acc[2][c] = __builtin_amdgcn_mfma_f32_16x16x32_f16(F2, bf[c], acc[2][c], 0, 0, 0); \
            acc[3][c] = __builtin_amdgcn_mfma_f32_16x16x32_f16(F3, bf[c], acc[3][c], 0, 0, 0); \
        }                                                                      \
    } while (0)

    __syncthreads();                  // Ss visible
    LOADA(afA0, afA1, afA2, afA3, 0); // A frags tile 0 -> set A (regs)
    LOADT(pbA0, pbA1, pbA2, pbA3, 0); // B tile 0 -> set A
    LOADT(pbB0, pbB1, pbB2, pbB3, 1); // B tile 1 -> set B
    STORET(pbA0, pbA1, pbA2, pbA3, 0);
    __syncthreads();

    for (int kp = 0; kp < KITER; kp += 2) {
        // even half-iter: compute tile kp (buf0, afA); prefetch A kp+1, B kp+2
        LOADA(afB0, afB1, afB2, afB3, kp + 1);
        if (kp + 2 < KITER) LOADT(pbA0, pbA1, pbA2, pbA3, kp + 2);
        FRAGS_MFMA(0, afA0, afA1, afA2, afA3);
        STORET(pbB0, pbB1, pbB2, pbB3, 1);    // B tile kp+1 (loaded 1 iter ago)
        __syncthreads();

        // odd half-iter: compute tile kp+1 (buf1, afB); prefetch A kp+2, B kp+3
        if (kp + 2 < KITER) LOADA(afA0, afA1, afA2, afA3, kp + 2);
        if (kp + 3 < KITER) LOADT(pbB0, pbB1, pbB2, pbB3, kp + 3);
        FRAGS_MFMA(1, afB0, afB1, afB2, afB3);
        if (kp + 2 < KITER)
            STORET(pbA0, pbA1, pbA2, pbA3, 0); // B tile kp+2 (loaded 1 iter ago)
        __syncthreads();
    }

    // ---- epilogue: atomic accumulate (C/D layout col=lane&15, row=quad*4+reg) ----
#pragma unroll
    for (int c = 0; c < 4; c++) {
        int col = gn0 + wn * 64 + c * 16 + l16;
#pragma unroll
        for (int r = 0; r < 4; r++) {
            int row0 = gm0 + wm * 64 + r * 16 + quad * 4;
#pragma unroll
            for (int e = 0; e < 4; e++)
                atomicAdd(&out[(size_t)(row0 + e) * NDIM + col], acc[r][c][e]);
        }
    }
#undef LOADA
#undef LOADT
#undef STORET
#undef FRAGS_MFMA
}

extern "C" void kernel_launch(void* const* d_in, const int* in_sizes, int n_in,
                              void* d_out, int out_size, void* d_ws, size_t ws_size,
                              hipStream_t stream) {
    const float* x = (const float*)d_in[0];
    const float* hw = (const float*)d_in[1];
    const float* bias = (const float*)d_in[2];
    const int* rn = (const int*)d_in[3];
    float* out = (float*)d_out;

    char* ws = (char*)d_ws;
    __half* xh = (__half*)ws;                          // 8 MB : x as f16
    __half* hh = (__half*)(ws + (8u << 20));           // 8 MB : hashed_weight as f16
    int* starts = (int*)(ws + (16u << 20));            // 256 KB : tile start table

    hipLaunchKernelGGL(prep_kernel, dim3(12544), dim3(256), 0, stream,
                       x, hw, bias, rn, xh, hh, starts, out);
    hipLaunchKernelGGL(gemm_kernel, dim3(512), dim3(512), 0, stream, xh, hh, starts, out);
}

// Round 9
// 260.856 us; speedup vs baseline: 1.0165x; 1.0165x over previous
//
#include <hip/hip_runtime.h>
#include <hip/hip_fp16.h>

#define NDIM 8192
#define KDIM 8192
#define NT 256          // N / 32 hash tiles
#define MOD2 4193281    // HASH_SIZE - 32*32 + 1
#define PRIME 2038074743LL

#define BM 256
#define BN 128
#define BK 32
#define KITER 32        // (KDIM/8)/BK, split-K = 8
#define BSLAB 1032      // halves per k-octet slab (128*8 + 8 pad; phase-balanced)

typedef _Float16 half8 __attribute__((ext_vector_type(8)));
typedef float floatx4 __attribute__((ext_vector_type(4)));

// ---------------- fused prepass: cvt fp32->f16, out=bias, ROBE-Z starts ----------------
__global__ __launch_bounds__(256) void prep_kernel(const float* __restrict__ x,
                                                   const float* __restrict__ hw,
                                                   const float* __restrict__ bias,
                                                   const int* __restrict__ rn,
                                                   __half* __restrict__ xh,
                                                   __half* __restrict__ hh,
                                                   int* __restrict__ starts,
                                                   float* __restrict__ out) {
    int b = blockIdx.x;
    int tid = threadIdx.x;
    if (b < 8192) {                       // cvt: 2M threads x 4 floats
        int i = b * 256 + tid;
        const float4* s; __half2* d; int j;
        if (i < (1 << 20)) { s = (const float4*)x;  d = (__half2*)xh; j = i; }
        else               { s = (const float4*)hw; d = (__half2*)hh; j = i - (1 << 20); }
        float4 v = s[j];
        d[j * 2]     = __floats2half2_rn(v.x, v.y);
        d[j * 2 + 1] = __floats2half2_rn(v.z, v.w);
    } else if (b < 8192 + 4096) {         // init: out = bias (atomic targets)
        int i = (b - 8192) * 256 + tid;
        float4 bv = *(const float4*)(bias + ((i & 2047) << 2));
        ((float4*)out)[i] = bv;
    } else {                              // starts: 64K hash tile offsets
        int t = (b - 12288) * 256 + tid;
        bool is64 = (rn[1] == 0 && rn[3] == 0);   // int64 input: words 1,3 are hi-halves
        long long R1 = is64 ? rn[2] : rn[1];
        long long R2 = is64 ? rn[4] : rn[2];
        long long R3 = is64 ? rn[6] : rn[3];
        long long k_id = t >> 8, n_id = t & 255;
        long long v = (k_id * R3 + n_id * R2 + R1) % PRIME;
        starts[t] = (int)(v % MOD2);
    }
}

// async global->LDS, 16B per lane; LDS dest = wave-uniform base + lane*16 (HW)
__device__ __forceinline__ void gload16(const __half* g, __half* l) {
    __builtin_amdgcn_global_load_lds((const __attribute__((address_space(1))) void*)g,
                                     (__attribute__((address_space(3))) void*)l, 16, 0, 0);
}

// ---------------- main GEMM: split-K=8, 256x128 block, dist-2 B prefetch ----------------
// R7-proven structure (122.1us at split-K=4). ONE change: split-K 4->8 so grid =
// 1024 blocks -> 3 resident blocks/CU (50.7KB LDS, 24 waves/CU vs 16) for
// barrier-desynchronized latency hiding. A via global_load_lds w=16 (swizzled
// global source, linear LDS dest, same XOR on read); B gather+pack (swizzled).
__global__ __launch_bounds__(512, 3) void gemm_kernel(
    const __half* __restrict__ xh, const __half* __restrict__ hh,
    const int* __restrict__ starts, float* __restrict__ out) {
    __shared__ __align__(16) __half As[2][BM * 32];        // [m][k] linear, swizzled chunks
    __shared__ __align__(16) __half Bs[2][4 * BSLAB];      // [k-octet][n][8] k-runs, swizzled
    __shared__ int Ss[KITER * 4];                          // per-block starts table

    const int tid = threadIdx.x;
    const int lane = tid & 63;
    const int wave = tid >> 6;       // 0..7
    const int wm = wave >> 1;        // 0..3 : 64-row strip
    const int wn = wave & 1;         // 0..1 : 64-col strip
    const int quad = lane >> 4;
    const int l16 = lane & 15;

    const int i = blockIdx.x;        // 1024 blocks = 8 ks x 2 m x 64 n
    const int ks = i & 7;
    const int m_blk = (i >> 3) & 1;
    const int n_blk = i >> 4;        // 0..63
    const int gm0 = m_blk * BM;
    const int gn0 = n_blk * BN;
    const int kt0 = ks * KITER;
    const int n_id0 = n_blk * 4;     // 4 hash tiles per block

    if (tid < KITER * 4) {
        int kp = tid >> 2, tile = tid & 3;
        Ss[tid] = starts[(kt0 + kp) * NT + n_id0 + tile];
    }

    // ---- A staging via global_load_lds: wave t covers rows t*16..t*16+15 per instr ----
    // swizzle: LDS chunk-pos p of row holds global chunk p ^ ((row>>1)&3).
    const int a_t = wave * 2;                              // first of this wave's 2 instrs
    const int a_chunk = (lane & 3) ^ ((lane >> 3) & 3);    // swizzled global chunk
    const __half* a_g0 = xh + (size_t)(gm0 + a_t * 16 + (lane >> 2)) * KDIM
                         + kt0 * 32 + a_chunk * 8;
    const __half* a_g1 = a_g0 + (size_t)16 * KDIM;         // rows +16

#define STAGE_A(buf_, kp_) do {                                                \
        gload16(a_g0 + (kp_) * 32, &As[buf_][a_t * 512]);                      \
        gload16(a_g1 + (kp_) * 32, &As[buf_][a_t * 512 + 512]);                \
    } while (0)

    // ---- B staging (reg-staged pack, R6-verbatim) ----
    const int b_tile = tid >> 7;              // 0..3
    const int t7 = tid & 127;
    const int b_np = t7 & 15;                 // n-pair
    const int b_kg = t7 >> 4;                 // 0..7 : 4-k group
    const int b_oct = b_kg >> 1;
    const unsigned b_base = b_oct * BSLAB;
    const unsigned b_pos = (b_tile * 32 + 2 * b_np) * 8 + (b_kg & 1) * 4;
    const unsigned bswz = (b_np & 4) << 1;    // = (n_even & 8)

    unsigned pbA0, pbA1, pbA2, pbA3, pbB0, pbB1, pbB2, pbB3;

#define LOADT(Q0, Q1, Q2, Q3, kp_) do {                                        \
        int st = Ss[(kp_) * 4 + b_tile];                                       \
        const __half* src = hh + st + b_kg * 128 + b_np * 2;                   \
        Q0 = *(const unsigned*)(src);                                          \
        Q1 = *(const unsigned*)(src + 32);                                     \
        Q2 = *(const unsigned*)(src + 64);                                     \
        Q3 = *(const unsigned*)(src + 96);                                     \
    } while (0)

#define STORET(Q0, Q1, Q2, Q3, buf_) do {                                      \
        unsigned lo0 = (Q0 & 0xffffu) | (Q1 << 16);                            \
        unsigned lo1 = (Q2 & 0xffffu) | (Q3 << 16);                            \
        unsigned hi0 = (Q0 >> 16) | (Q1 & 0xffff0000u);                        \
        unsigned hi1 = (Q2 >> 16) | (Q3 & 0xffff0000u);                        \
        uint2 e = {lo0, lo1}, o = {hi0, hi1};                                  \
        *(uint2*)&Bs[buf_][b_base + (b_pos ^ bswz)] = e;                       \
        *(uint2*)&Bs[buf_][b_base + ((b_pos + 8) ^ bswz)] = o;                 \
    } while (0)

    floatx4 acc[4][4];
#pragma unroll
    for (int r = 0; r < 4; r++)
#pragma unroll
        for (int c = 0; c < 4; c++)
            acc[r][c] = (floatx4){0.f, 0.f, 0.f, 0.f};

    const unsigned rswz = (unsigned)(l16 & 8);          // B read swizzle
    const unsigned a_rswz = (unsigned)((l16 >> 1) & 3); // A read chunk swizzle

#define FRAGS_MFMA(buf_) do {                                                  \
        half8 af[4], bf[4];                                                    \
        _Pragma("unroll")                                                      \
        for (int r = 0; r < 4; r++)                                            \
            af[r] = *(const half8*)&As[buf_][(unsigned)(wm * 64 + r * 16 + l16) * 32 \
                                             + ((quad ^ a_rswz) * 8)];         \
        _Pragma("unroll")                                                      \
        for (int c = 0; c < 4; c++)                                            \
            bf[c] = *(const half8*)&Bs[buf_][quad * BSLAB + ((unsigned)((wn * 64 + c * 16 + l16) * 8) ^ rswz)]; \
        _Pragma("unroll")                                                      \
        for (int r = 0; r < 4; r++)                                            \
            _Pragma("unroll")                                                  \
            for (int c = 0; c < 4; c++)                                        \
                acc[r][c] = __builtin_amdgcn_mfma_f32_16x16x32_f16(af[r], bf[c], acc[r][c], 0, 0, 0); \
    } while (0)

    __syncthreads();                  // Ss visible
    STAGE_A(0, 0);                    // A tile 0 -> buf0 (async)
    LOADT(pbA0, pbA1, pbA2, pbA3, 0); // B tile 0 -> set A
    LOADT(pbB0, pbB1, pbB2, pbB3, 1); // B tile 1 -> set B
    STORET(pbA0, pbA1, pbA2, pbA3, 0);
    __syncthreads();                  // drains vmcnt -> A(0) ready

    for (int kp = 0; kp < KITER; kp += 2) {
        // even half-iter: compute tile kp from buf0; stage tile kp+1 A into buf1
        STAGE_A(1, kp + 1);
        if (kp + 2 < KITER) LOADT(pbA0, pbA1, pbA2, pbA3, kp + 2);
        FRAGS_MFMA(0);
        STORET(pbB0, pbB1, pbB2, pbB3, 1);    // B tile kp+1 (loaded 1 iter ago)
        __syncthreads();

        // odd half-iter: compute tile kp+1 from buf1; stage tile kp+2 A into buf0
        if (kp + 2 < KITER) STAGE_A(0, kp + 2);
        if (kp + 3 < KITER) LOADT(pbB0, pbB1, pbB2, pbB3, kp + 3);
        FRAGS_MFMA(1);
        if (kp + 2 < KITER)
            STORET(pbA0, pbA1, pbA2, pbA3, 0); // B tile kp+2 (loaded 1 iter ago)
        __syncthreads();
    }

    // ---- epilogue: atomic accumulate (C/D layout col=lane&15, row=quad*4+reg) ----
#pragma unroll
    for (int c = 0; c < 4; c++) {
        int col = gn0 + wn * 64 + c * 16 + l16;
#pragma unroll
        for (int r = 0; r < 4; r++) {
            int row0 = gm0 + wm * 64 + r * 16 + quad * 4;
#pragma unroll
            for (int e = 0; e < 4; e++)
                atomicAdd(&out[(size_t)(row0 + e) * NDIM + col], acc[r][c][e]);
        }
    }
#undef LOADT
#undef STORET
#undef FRAGS_MFMA
#undef STAGE_A
}

extern "C" void kernel_launch(void* const* d_in, const int* in_sizes, int n_in,
                              void* d_out, int out_size, void* d_ws, size_t ws_size,
                              hipStream_t stream) {
    const float* x = (const float*)d_in[0];
    const float* hw = (const float*)d_in[1];
    const float* bias = (const float*)d_in[2];
    const int* rn = (const int*)d_in[3];
    float* out = (float*)d_out;

    char* ws = (char*)d_ws;
    __half* xh = (__half*)ws;                          // 8 MB : x as f16
    __half* hh = (__half*)(ws + (8u << 20));           // 8 MB : hashed_weight as f16
    int* starts = (int*)(ws + (16u << 20));            // 256 KB : tile start table

    hipLaunchKernelGGL(prep_kernel, dim3(12544), dim3(256), 0, stream,
                       x, hw, bias, rn, xh, hh, starts, out);
    hipLaunchKernelGGL(gemm_kernel, dim3(1024), dim3(512), 0, stream, xh, hh, starts, out);
}

// Round 10
// 201.277 us; speedup vs baseline: 1.3174x; 1.2960x over previous
//
#include <hip/hip_runtime.h>
#include <hip/hip_fp16.h>

#define NDIM 8192
#define KDIM 8192
#define NT 256          // N / 32 hash tiles
#define MOD2 4193281    // HASH_SIZE - 32*32 + 1
#define PRIME 2038074743LL

#define BM 256
#define BN 128
#define BK 32
#define KITER 64        // (KDIM/4)/BK, split-K = 4
#define BSLAB 1032      // halves per k-octet slab (128*8 + 8 pad; phase-balanced)

typedef _Float16 half8 __attribute__((ext_vector_type(8)));
typedef float floatx4 __attribute__((ext_vector_type(4)));

// ---------------- fused prepass: cvt fp32->f16, out=bias, ROBE-Z starts ----------------
__global__ __launch_bounds__(256) void prep_kernel(const float* __restrict__ x,
                                                   const float* __restrict__ hw,
                                                   const float* __restrict__ bias,
                                                   const int* __restrict__ rn,
                                                   __half* __restrict__ xh,
                                                   __half* __restrict__ hh,
                                                   int* __restrict__ starts,
                                                   float* __restrict__ out) {
    int b = blockIdx.x;
    int tid = threadIdx.x;
    if (b < 8192) {                       // cvt: 2M threads x 4 floats
        int i = b * 256 + tid;
        const float4* s; __half2* d; int j;
        if (i < (1 << 20)) { s = (const float4*)x;  d = (__half2*)xh; j = i; }
        else               { s = (const float4*)hw; d = (__half2*)hh; j = i - (1 << 20); }
        float4 v = s[j];
        d[j * 2]     = __floats2half2_rn(v.x, v.y);
        d[j * 2 + 1] = __floats2half2_rn(v.z, v.w);
    } else if (b < 8192 + 4096) {         // init: out = bias (atomic targets)
        int i = (b - 8192) * 256 + tid;
        float4 bv = *(const float4*)(bias + ((i & 2047) << 2));
        ((float4*)out)[i] = bv;
    } else {                              // starts: 64K hash tile offsets
        int t = (b - 12288) * 256 + tid;
        bool is64 = (rn[1] == 0 && rn[3] == 0);   // int64 input: words 1,3 are hi-halves
        long long R1 = is64 ? rn[2] : rn[1];
        long long R2 = is64 ? rn[4] : rn[2];
        long long R3 = is64 ? rn[6] : rn[3];
        long long k_id = t >> 8, n_id = t & 255;
        long long v = (k_id * R3 + n_id * R2 + R1) % PRIME;
        starts[t] = (int)(v % MOD2);
    }
}

// async global->LDS, 16B per lane; LDS dest = wave-uniform base + lane*16 (HW)
__device__ __forceinline__ void gload16(const __half* g, __half* l) {
    __builtin_amdgcn_global_load_lds((const __attribute__((address_space(1))) void*)g,
                                     (__attribute__((address_space(3))) void*)l, 16, 0, 0);
}

// Counted-wait barrier (T4): vmcnt(4) drains the 2 A global_load_lds (oldest,
// whose LDS data is read right after the barrier) while leaving the 4 newest
// B gathers (register dests, consumed a full half-iter later) in flight.
// lgkmcnt(0) drains all ds ops (WAR-safe buffer swap). gfx9 simm16 encoding:
// vmcnt[3:0]=4 | expcnt[6:4]=7 (no wait) | lgkmcnt[11:8]=0  -> 0x0074.
#define BARC() do {                                             \
        __builtin_amdgcn_s_waitcnt(0x0074);                     \
        __builtin_amdgcn_s_barrier();                           \
    } while (0)

// ---------------- main GEMM: split-K=4, 256x128 block, dist-2 B prefetch ----------------
// R7-proven data path (122.1us). ONE change vs R7: the 3 steady-state barriers
// (and 2nd prologue barrier) use counted vmcnt(4) instead of __syncthreads'
// vmcnt(0) -> B-gathers keep their natural 1-half-iter slack instead of being
// force-drained ~300cy after issue.
__global__ __launch_bounds__(512, 4) void gemm_kernel(
    const __half* __restrict__ xh, const __half* __restrict__ hh,
    const int* __restrict__ starts, float* __restrict__ out) {
    __shared__ __align__(16) __half As[2][BM * 32];        // [m][k] linear, swizzled chunks
    __shared__ __align__(16) __half Bs[2][4 * BSLAB];      // [k-octet][n][8] k-runs, swizzled
    __shared__ int Ss[KITER * 4];                          // per-block starts table

    const int tid = threadIdx.x;
    const int lane = tid & 63;
    const int wave = tid >> 6;       // 0..7
    const int wm = wave >> 1;        // 0..3 : 64-row strip
    const int wn = wave & 1;         // 0..1 : 64-col strip
    const int quad = lane >> 4;
    const int l16 = lane & 15;

    const int i = blockIdx.x;        // 512 blocks
    const int ks = i & 3;
    const int m_blk = (i >> 2) & 1;
    const int n_blk = i >> 3;        // 0..63
    const int gm0 = m_blk * BM;
    const int gn0 = n_blk * BN;
    const int kt0 = ks * KITER;
    const int n_id0 = n_blk * 4;     // 4 hash tiles per block

    if (tid < KITER * 4) {
        int kp = tid >> 2, tile = tid & 3;
        Ss[tid] = starts[(kt0 + kp) * NT + n_id0 + tile];
    }

    // ---- A staging via global_load_lds: wave t covers rows t*16..t*16+15 per instr ----
    // swizzle: LDS chunk-pos p of row holds global chunk p ^ ((row>>1)&3).
    const int a_t = wave * 2;                              // first of this wave's 2 instrs
    const int a_chunk = (lane & 3) ^ ((lane >> 3) & 3);    // swizzled global chunk
    const __half* a_g0 = xh + (size_t)(gm0 + a_t * 16 + (lane >> 2)) * KDIM
                         + kt0 * 32 + a_chunk * 8;
    const __half* a_g1 = a_g0 + (size_t)16 * KDIM;         // rows +16

#define STAGE_A(buf_, kp_) do {                                                \
        gload16(a_g0 + (kp_) * 32, &As[buf_][a_t * 512]);                      \
        gload16(a_g1 + (kp_) * 32, &As[buf_][a_t * 512 + 512]);                \
    } while (0)

    // ---- B staging (reg-staged pack, R6-verbatim) ----
    const int b_tile = tid >> 7;              // 0..3
    const int t7 = tid & 127;
    const int b_np = t7 & 15;                 // n-pair
    const int b_kg = t7 >> 4;                 // 0..7 : 4-k group
    const int b_oct = b_kg >> 1;
    const unsigned b_base = b_oct * BSLAB;
    const unsigned b_pos = (b_tile * 32 + 2 * b_np) * 8 + (b_kg & 1) * 4;
    const unsigned bswz = (b_np & 4) << 1;    // = (n_even & 8)

    unsigned pbA0, pbA1, pbA2, pbA3, pbB0, pbB1, pbB2, pbB3;

#define LOADT(Q0, Q1, Q2, Q3, kp_) do {                                        \
        int st = Ss[(kp_) * 4 + b_tile];                                       \
        const __half* src = hh + st + b_kg * 128 + b_np * 2;                   \
        Q0 = *(const unsigned*)(src);                                          \
        Q1 = *(const unsigned*)(src + 32);                                     \
        Q2 = *(const unsigned*)(src + 64);                                     \
        Q3 = *(const unsigned*)(src + 96);                                     \
    } while (0)

#define STORET(Q0, Q1, Q2, Q3, buf_) do {                                      \
        unsigned lo0 = (Q0 & 0xffffu) | (Q1 << 16);                            \
        unsigned lo1 = (Q2 & 0xffffu) | (Q3 << 16);                            \
        unsigned hi0 = (Q0 >> 16) | (Q1 & 0xffff0000u);                        \
        unsigned hi1 = (Q2 >> 16) | (Q3 & 0xffff0000u);                        \
        uint2 e = {lo0, lo1}, o = {hi0, hi1};                                  \
        *(uint2*)&Bs[buf_][b_base + (b_pos ^ bswz)] = e;                       \
        *(uint2*)&Bs[buf_][b_base + ((b_pos + 8) ^ bswz)] = o;                 \
    } while (0)

    floatx4 acc[4][4];
#pragma unroll
    for (int r = 0; r < 4; r++)
#pragma unroll
        for (int c = 0; c < 4; c++)
            acc[r][c] = (floatx4){0.f, 0.f, 0.f, 0.f};

    const unsigned rswz = (unsigned)(l16 & 8);          // B read swizzle
    const unsigned a_rswz = (unsigned)((l16 >> 1) & 3); // A read chunk swizzle

#define FRAGS_MFMA(buf_) do {                                                  \
        half8 af[4], bf[4];                                                    \
        _Pragma("unroll")                                                      \
        for (int r = 0; r < 4; r++)                                            \
            af[r] = *(const half8*)&As[buf_][(unsigned)(wm * 64 + r * 16 + l16) * 32 \
                                             + ((quad ^ a_rswz) * 8)];         \
        _Pragma("unroll")                                                      \
        for (int c = 0; c < 4; c++)                                            \
            bf[c] = *(const half8*)&Bs[buf_][quad * BSLAB + ((unsigned)((wn * 64 + c * 16 + l16) * 8) ^ rswz)]; \
        _Pragma("unroll")                                                      \
        for (int r = 0; r < 4; r++)                                            \
            _Pragma("unroll")                                                  \
            for (int c = 0; c < 4; c++)                                        \
                acc[r][c] = __builtin_amdgcn_mfma_f32_16x16x32_f16(af[r], bf[c], acc[r][c], 0, 0, 0); \
    } while (0)

    __syncthreads();                  // Ss visible (full drain, once)
    STAGE_A(0, 0);                    // A tile 0 -> buf0 (async, 2 gloads)
    LOADT(pbA0, pbA1, pbA2, pbA3, 0); // B tile 0 -> set A
    LOADT(pbB0, pbB1, pbB2, pbB3, 1); // B tile 1 -> set B
    STORET(pbA0, pbA1, pbA2, pbA3, 0);  // implicit vmcnt wait covers A-gloads too
    BARC();                           // leaves B tile-1 gathers in flight

    for (int kp = 0; kp < KITER; kp += 2) {
        // even half-iter: compute tile kp from buf0; stage tile kp+1 A into buf1
        STAGE_A(1, kp + 1);
        if (kp + 2 < KITER) LOADT(pbA0, pbA1, pbA2, pbA3, kp + 2);
        FRAGS_MFMA(0);
        STORET(pbB0, pbB1, pbB2, pbB3, 1);    // B tile kp+1 (loaded 1 iter ago)
        BARC();                       // drains A-gloads (buf1); B kp+2 stays in flight

        // odd half-iter: compute tile kp+1 from buf1; stage tile kp+2 A into buf0
        if (kp + 2 < KITER) STAGE_A(0, kp + 2);
        if (kp + 3 < KITER) LOADT(pbB0, pbB1, pbB2, pbB3, kp + 3);
        FRAGS_MFMA(1);
        if (kp + 2 < KITER)
            STORET(pbA0, pbA1, pbA2, pbA3, 0); // B tile kp+2 (loaded 1 iter ago)
        BARC();                       // drains A-gloads (buf0); B kp+3 stays in flight
    }

    // ---- epilogue: atomic accumulate (C/D layout col=lane&15, row=quad*4+reg) ----
#pragma unroll
    for (int c = 0; c < 4; c++) {
        int col = gn0 + wn * 64 + c * 16 + l16;
#pragma unroll
        for (int r = 0; r < 4; r++) {
            int row0 = gm0 + wm * 64 + r * 16 + quad * 4;
#pragma unroll
            for (int e = 0; e < 4; e++)
                atomicAdd(&out[(size_t)(row0 + e) * NDIM + col], acc[r][c][e]);
        }
    }
#undef LOADT
#undef STORET
#undef FRAGS_MFMA
#undef STAGE_A
}

extern "C" void kernel_launch(void* const* d_in, const int* in_sizes, int n_in,
                              void* d_out, int out_size, void* d_ws, size_t ws_size,
                              hipStream_t stream) {
    const float* x = (const float*)d_in[0];
    const float* hw = (const float*)d_in[1];
    const float* bias = (const float*)d_in[2];
    const int* rn = (const int*)d_in[3];
    float* out = (float*)d_out;

    char* ws = (char*)d_ws;
    __half* xh = (__half*)ws;                          // 8 MB : x as f16
    __half* hh = (__half*)(ws + (8u << 20));           // 8 MB : hashed_weight as f16
    int* starts = (int*)(ws + (16u << 20));            // 256 KB : tile start table

    hipLaunchKernelGGL(prep_kernel, dim3(12544), dim3(256), 0, stream,
                       x, hw, bias, rn, xh, hh, starts, out);
    hipLaunchKernelGGL(gemm_kernel, dim3(512), dim3(512), 0, stream, xh, hh, starts, out);
}

// Round 12
// 192.202 us; speedup vs baseline: 1.3796x; 1.0472x over previous
//
#include <hip/hip_runtime.h>
#include <hip/hip_fp16.h>

#define NDIM 8192
#define KDIM 8192
#define NT 256          // N / 32 hash tiles
#define MOD2 4193281    // HASH_SIZE - 32*32 + 1
#define PRIME 2038074743LL

#define BM 256
#define BN 128
#define BK 32
#define KITER 64        // (KDIM/4)/BK, split-K = 4
#define BSLAB 1032      // halves per k-octet slab (128*8 + 8 pad; phase-balanced)

typedef _Float16 half8 __attribute__((ext_vector_type(8)));
typedef float floatx4 __attribute__((ext_vector_type(4)));

// ---------------- fused prepass: cvt fp32->f16, out=bias, ROBE-Z starts ----------------
__global__ __launch_bounds__(256) void prep_kernel(const float* __restrict__ x,
                                                   const float* __restrict__ hw,
                                                   const float* __restrict__ bias,
                                                   const int* __restrict__ rn,
                                                   __half* __restrict__ xh,
                                                   __half* __restrict__ hh,
                                                   int* __restrict__ starts,
                                                   float* __restrict__ out) {
    int b = blockIdx.x;
    int tid = threadIdx.x;
    if (b < 8192) {                       // cvt: 2M threads x 4 floats
        int i = b * 256 + tid;
        const float4* s; __half2* d; int j;
        if (i < (1 << 20)) { s = (const float4*)x;  d = (__half2*)xh; j = i; }
        else               { s = (const float4*)hw; d = (__half2*)hh; j = i - (1 << 20); }
        float4 v = s[j];
        d[j * 2]     = __floats2half2_rn(v.x, v.y);
        d[j * 2 + 1] = __floats2half2_rn(v.z, v.w);
    } else if (b < 8192 + 4096) {         // init: out = bias (atomic targets)
        int i = (b - 8192) * 256 + tid;
        float4 bv = *(const float4*)(bias + ((i & 2047) << 2));
        ((float4*)out)[i] = bv;
    } else {                              // starts: 64K hash tile offsets
        int t = (b - 12288) * 256 + tid;
        bool is64 = (rn[1] == 0 && rn[3] == 0);   // int64 input: words 1,3 are hi-halves
        long long R1 = is64 ? rn[2] : rn[1];
        long long R2 = is64 ? rn[4] : rn[2];
        long long R3 = is64 ? rn[6] : rn[3];
        long long k_id = t >> 8, n_id = t & 255;
        long long v = (k_id * R3 + n_id * R2 + R1) % PRIME;
        starts[t] = (int)(v % MOD2);
    }
}

// async global->LDS, 16B per lane; LDS dest = wave-uniform base + lane*16 (HW)
__device__ __forceinline__ void gload16(const __half* g, __half* l) {
    __builtin_amdgcn_global_load_lds((const __attribute__((address_space(1))) void*)g,
                                     (__attribute__((address_space(3))) void*)l, 16, 0, 0);
}

#define SBAR() __builtin_amdgcn_sched_barrier(0)

// ---------------- main GEMM: split-K=4, 256x128 block, per-phase interleave ----------------
// R10 data path (120.3us), T3 phase shape. R11 race fixed:
//  (1) final even-phase barrier drains vmcnt(0) (tail STAGE_A had no younger
//      loads behind it, so vmcnt(4) was a no-op -> stale As[1] read for tile 63);
//  (2) sched_barrier(0) pins phase boundaries (raw s_barrier is not a memory
//      fence; prevents ds_read hoist / ds_write sink across barriers).
__global__ __launch_bounds__(512, 4) void gemm_kernel(
    const __half* __restrict__ xh, const __half* __restrict__ hh,
    const int* __restrict__ starts, float* __restrict__ out) {
    __shared__ __align__(16) __half As[2][BM * 32];        // [m][k] linear, swizzled chunks
    __shared__ __align__(16) __half Bs[2][4 * BSLAB];      // [k-octet][n][8] k-runs, swizzled
    __shared__ int Ss[KITER * 4];                          // per-block starts table

    const int tid = threadIdx.x;
    const int lane = tid & 63;
    const int wave = tid >> 6;       // 0..7
    const int wm = wave >> 1;        // 0..3 : 64-row strip
    const int wn = wave & 1;         // 0..1 : 64-col strip
    const int quad = lane >> 4;
    const int l16 = lane & 15;

    const int i = blockIdx.x;        // 512 blocks
    const int ks = i & 3;
    const int m_blk = (i >> 2) & 1;
    const int n_blk = i >> 3;        // 0..63
    const int gm0 = m_blk * BM;
    const int gn0 = n_blk * BN;
    const int kt0 = ks * KITER;
    const int n_id0 = n_blk * 4;     // 4 hash tiles per block

    if (tid < KITER * 4) {
        int kp = tid >> 2, tile = tid & 3;
        Ss[tid] = starts[(kt0 + kp) * NT + n_id0 + tile];
    }

    // ---- A staging via global_load_lds: wave t covers rows t*16..t*16+15 per instr ----
    const int a_t = wave * 2;                              // first of this wave's 2 instrs
    const int a_chunk = (lane & 3) ^ ((lane >> 3) & 3);    // swizzled global chunk
    const __half* a_g0 = xh + (size_t)(gm0 + a_t * 16 + (lane >> 2)) * KDIM
                         + kt0 * 32 + a_chunk * 8;
    const __half* a_g1 = a_g0 + (size_t)16 * KDIM;         // rows +16

#define STAGE_A(buf_, kp_) do {                                                \
        gload16(a_g0 + (kp_) * 32, &As[buf_][a_t * 512]);                      \
        gload16(a_g1 + (kp_) * 32, &As[buf_][a_t * 512 + 512]);                \
    } while (0)

    // ---- B staging (reg-staged pack, R6-verbatim) ----
    const int b_tile = tid >> 7;              // 0..3
    const int t7 = tid & 127;
    const int b_np = t7 & 15;                 // n-pair
    const int b_kg = t7 >> 4;                 // 0..7 : 4-k group
    const int b_oct = b_kg >> 1;
    const unsigned b_base = b_oct * BSLAB;
    const unsigned b_pos = (b_tile * 32 + 2 * b_np) * 8 + (b_kg & 1) * 4;
    const unsigned bswz = (b_np & 4) << 1;    // = (n_even & 8)

    unsigned pbA0, pbA1, pbA2, pbA3, pbB0, pbB1, pbB2, pbB3;

#define LOADT(Q0, Q1, Q2, Q3, kp_) do {                                        \
        int st = Ss[(kp_) * 4 + b_tile];                                       \
        const __half* src = hh + st + b_kg * 128 + b_np * 2;                   \
        Q0 = *(const unsigned*)(src);                                          \
        Q1 = *(const unsigned*)(src + 32);                                     \
        Q2 = *(const unsigned*)(src + 64);                                     \
        Q3 = *(const unsigned*)(src + 96);                                     \
    } while (0)

#define STORET(Q0, Q1, Q2, Q3, buf_) do {                                      \
        unsigned lo0 = (Q0 & 0xffffu) | (Q1 << 16);                            \
        unsigned lo1 = (Q2 & 0xffffu) | (Q3 << 16);                            \
        unsigned hi0 = (Q0 >> 16) | (Q1 & 0xffff0000u);                        \
        unsigned hi1 = (Q2 >> 16) | (Q3 & 0xffff0000u);                        \
        uint2 e = {lo0, lo1}, o = {hi0, hi1};                                  \
        *(uint2*)&Bs[buf_][b_base + (b_pos ^ bswz)] = e;                       \
        *(uint2*)&Bs[buf_][b_base + ((b_pos + 8) ^ bswz)] = o;                 \
    } while (0)

    floatx4 acc[4][4];
#pragma unroll
    for (int r = 0; r < 4; r++)
#pragma unroll
        for (int c = 0; c < 4; c++)
            acc[r][c] = (floatx4){0.f, 0.f, 0.f, 0.f};

    const unsigned rswz = (unsigned)(l16 & 8);          // B read swizzle
    const unsigned a_rswz = (unsigned)((l16 >> 1) & 3); // A read chunk swizzle

    half8 fa0, fa1, fa2, fa3, fb0, fb1, fb2, fb3;       // frags live across mid-barrier

#define READF(buf_) do {                                                       \
        fa0 = *(const half8*)&As[buf_][(unsigned)(wm * 64 +  0 + l16) * 32 + ((quad ^ a_rswz) * 8)]; \
        fa1 = *(const half8*)&As[buf_][(unsigned)(wm * 64 + 16 + l16) * 32 + ((quad ^ a_rswz) * 8)]; \
        fa2 = *(const half8*)&As[buf_][(unsigned)(wm * 64 + 32 + l16) * 32 + ((quad ^ a_rswz) * 8)]; \
        fa3 = *(const half8*)&As[buf_][(unsigned)(wm * 64 + 48 + l16) * 32 + ((quad ^ a_rswz) * 8)]; \
        fb0 = *(const half8*)&Bs[buf_][quad * BSLAB + ((unsigned)((wn * 64 +  0 + l16) * 8) ^ rswz)]; \
        fb1 = *(const half8*)&Bs[buf_][quad * BSLAB + ((unsigned)((wn * 64 + 16 + l16) * 8) ^ rswz)]; \
        fb2 = *(const half8*)&Bs[buf_][quad * BSLAB + ((unsigned)((wn * 64 + 32 + l16) * 8) ^ rswz)]; \
        fb3 = *(const half8*)&Bs[buf_][quad * BSLAB + ((unsigned)((wn * 64 + 48 + l16) * 8) ^ rswz)]; \
    } while (0)

#define MFMAC() do {                                                           \
        __builtin_amdgcn_s_setprio(1);                                         \
        acc[0][0] = __builtin_amdgcn_mfma_f32_16x16x32_f16(fa0, fb0, acc[0][0], 0, 0, 0); \
        acc[1][0] = __builtin_amdgcn_mfma_f32_16x16x32_f16(fa1, fb0, acc[1][0], 0, 0, 0); \
        acc[2][0] = __builtin_amdgcn_mfma_f32_16x16x32_f16(fa2, fb0, acc[2][0], 0, 0, 0); \
        acc[3][0] = __builtin_amdgcn_mfma_f32_16x16x32_f16(fa3, fb0, acc[3][0], 0, 0, 0); \
        acc[0][1] = __builtin_amdgcn_mfma_f32_16x16x32_f16(fa0, fb1, acc[0][1], 0, 0, 0); \
        acc[1][1] = __builtin_amdgcn_mfma_f32_16x16x32_f16(fa1, fb1, acc[1][1], 0, 0, 0); \
        acc[2][1] = __builtin_amdgcn_mfma_f32_16x16x32_f16(fa2, fb1, acc[2][1], 0, 0, 0); \
        acc[3][1] = __builtin_amdgcn_mfma_f32_16x16x32_f16(fa3, fb1, acc[3][1], 0, 0, 0); \
        acc[0][2] = __builtin_amdgcn_mfma_f32_16x16x32_f16(fa0, fb2, acc[0][2], 0, 0, 0); \
        acc[1][2] = __builtin_amdgcn_mfma_f32_16x16x32_f16(fa1, fb2, acc[1][2], 0, 0, 0); \
        acc[2][2] = __builtin_amdgcn_mfma_f32_16x16x32_f16(fa2, fb2, acc[2][2], 0, 0, 0); \
        acc[3][2] = __builtin_amdgcn_mfma_f32_16x16x32_f16(fa3, fb2, acc[3][2], 0, 0, 0); \
        acc[0][3] = __builtin_amdgcn_mfma_f32_16x16x32_f16(fa0, fb3, acc[0][3], 0, 0, 0); \
        acc[1][3] = __builtin_amdgcn_mfma_f32_16x16x32_f16(fa1, fb3, acc[1][3], 0, 0, 0); \
        acc[2][3] = __builtin_amdgcn_mfma_f32_16x16x32_f16(fa2, fb3, acc[2][3], 0, 0, 0); \
        acc[3][3] = __builtin_amdgcn_mfma_f32_16x16x32_f16(fa3, fb3, acc[3][3], 0, 0, 0); \
        __builtin_amdgcn_s_setprio(0);                                         \
    } while (0)

    __syncthreads();                  // Ss visible (full drain, once)
    STAGE_A(0, 0);                    // A tile 0 -> buf0 (async, 2 gloads)
    LOADT(pbA0, pbA1, pbA2, pbA3, 0); // B tile 0 -> set A
    LOADT(pbB0, pbB1, pbB2, pbB3, 1); // B tile 1 -> set B
    STORET(pbA0, pbA1, pbA2, pbA3, 0);  // implicit vmcnt wait covers A-gloads too
    __syncthreads();                  // tile 0 fully staged, all vm drained

    for (int kp = 0; kp < KITER; kp += 2) {
        // ---- phase even: tile kp (buf0) ----
        READF(0);                                   // 8 ds_reads issued
        STAGE_A(1, kp + 1);                         // A tile kp+1 -> buf1
        if (kp + 2 < KITER) LOADT(pbA0, pbA1, pbA2, pbA3, kp + 2);
        SBAR();
        __builtin_amdgcn_s_barrier();               // rendezvous: hide read latency
        SBAR();
        MFMAC();                                    // compiler inserts lgkmcnt before use
        STORET(pbB0, pbB1, pbB2, pbB3, 1);          // B tile kp+1 -> buf1
        SBAR();
        if (kp + 2 < KITER)
            __builtin_amdgcn_s_waitcnt(0x0074);     // vmcnt(4): drains STAGE_A, pbA in flight
        else
            __builtin_amdgcn_s_waitcnt(0x0070);     // TAIL: vmcnt(0) — STAGE_A has no
                                                    // younger loads behind it (R11 race fix)
        __builtin_amdgcn_s_barrier();
        SBAR();

        // ---- phase odd: tile kp+1 (buf1) ----
        READF(1);
        if (kp + 2 < KITER) STAGE_A(0, kp + 2);
        if (kp + 3 < KITER) LOADT(pbB0, pbB1, pbB2, pbB3, kp + 3);
        SBAR();
        __builtin_amdgcn_s_barrier();
        SBAR();
        MFMAC();
        if (kp + 2 < KITER)
            STORET(pbA0, pbA1, pbA2, pbA3, 0);      // B tile kp+2 -> buf0
        SBAR();
        __builtin_amdgcn_s_waitcnt(0x0074);         // vmcnt(4) lgkmcnt(0)
        __builtin_amdgcn_s_barrier();
        SBAR();
    }

    // ---- epilogue: atomic accumulate (C/D layout col=lane&15, row=quad*4+reg) ----
#pragma unroll
    for (int c = 0; c < 4; c++) {
        int col = gn0 + wn * 64 + c * 16 + l16;
#pragma unroll
        for (int r = 0; r < 4; r++) {
            int row0 = gm0 + wm * 64 + r * 16 + quad * 4;
#pragma unroll
            for (int e = 0; e < 4; e++)
                atomicAdd(&out[(size_t)(row0 + e) * NDIM + col], acc[r][c][e]);
        }
    }
#undef LOADT
#undef STORET
#undef READF
#undef MFMAC
#undef STAGE_A
}

extern "C" void kernel_launch(void* const* d_in, const int* in_sizes, int n_in,
                              void* d_out, int out_size, void* d_ws, size_t ws_size,
                              hipStream_t stream) {
    const float* x = (const float*)d_in[0];
    const float* hw = (const float*)d_in[1];
    const float* bias = (const float*)d_in[2];
    const int* rn = (const int*)d_in[3];
    float* out = (float*)d_out;

    char* ws = (char*)d_ws;
    __half* xh = (__half*)ws;                          // 8 MB : x as f16
    __half* hh = (__half*)(ws + (8u << 20));           // 8 MB : hashed_weight as f16
    int* starts = (int*)(ws + (16u << 20));            // 256 KB : tile start table

    hipLaunchKernelGGL(prep_kernel, dim3(12544), dim3(256), 0, stream,
                       x, hw, bias, rn, xh, hh, starts, out);
    hipLaunchKernelGGL(gemm_kernel, dim3(512), dim3(512), 0, stream, xh, hh, starts, out);
}